// Round 18
// baseline (324.100 us; speedup 1.0000x reference)
//
#include <hip/hip_runtime.h>
#include <hip/hip_bf16.h>
#include <math.h>

#define B_   16
#define S_   4096
#define DIN  1024
#define V_   512
#define FOUT 120

typedef __attribute__((ext_vector_type(8))) short bf16x8;
typedef __attribute__((ext_vector_type(4))) float f32x4;

#define AS1 __attribute__((address_space(1)))
#define AS3 __attribute__((address_space(3)))

__device__ const float CSCALE = 0.1f / (64.0f * 4096.0f);
__device__ const float EPSF = 1e-5f;

__device__ inline void gl2lds16(const void* g, void* l) {
  __builtin_amdgcn_global_load_lds((const AS1 unsigned int*)g,
                                   (AS3 unsigned int*)l, 16, 0, 0);
}

// fp32 -> bf16 RNE
__device__ inline unsigned short f2b(float f) {
  unsigned u = __builtin_bit_cast(unsigned, f);
  unsigned r = (u + 0x7FFFu + ((u >> 16) & 1u)) >> 16;
  return (unsigned short)r;
}

__device__ inline bf16x8 pack8(float4 a, float4 b) {
  bf16x8 r;
  r[0] = (short)f2b(a.x); r[1] = (short)f2b(a.y);
  r[2] = (short)f2b(a.z); r[3] = (short)f2b(a.w);
  r[4] = (short)f2b(b.x); r[5] = (short)f2b(b.y);
  r[6] = (short)f2b(b.z); r[7] = (short)f2b(b.w);
  return r;
}

// Fused pre-pass: blocks 0..767 convert W (frag-major Wt, r7-r17-verified map);
// block 768 zeroes outacc.
__global__ __launch_bounds__(256) void msr_conv(
    const float* __restrict__ Wq, const float* __restrict__ Wk,
    const float* __restrict__ Wv, unsigned short* __restrict__ Wt,
    float* __restrict__ outacc) {
  const int bid = blockIdx.x;
  if (bid < 768) {
    int e = bid * 256 + threadIdx.x;
    int l = e & 63;
    int f = (e >> 6) % 24;
    int ck = (e >> 6) / 24;
    int k = ck & 31;
    int ct = ck >> 5;
    int nf = f / 3, g = f % 3;
    const float* W = (g == 0) ? Wq : (g == 1) ? Wk : Wv;
    int ch = ct * 128 + nf * 16 + (l & 15);
    const float* src = W + (size_t)ch * DIN + k * 32 + (l >> 4) * 8;
    float4 a = *(const float4*)src;
    float4 b = *(const float4*)(src + 4);
    *(bf16x8*)(Wt + (size_t)e * 8) = pack8(a, b);
  } else {
    for (int i = threadIdx.x; i < B_ * V_; i += 256) outacc[i] = 0.f;
  }
}

#define WAITVM3  asm volatile("s_waitcnt vmcnt(3)" ::: "memory")
#define WAITVM0  asm volatile("s_waitcnt vmcnt(0)" ::: "memory")
#define WAITLGKM asm volatile("s_waitcnt lgkmcnt(0)" ::: "memory")
#define SCHEDB   __builtin_amdgcn_sched_barrier(0)
#define BARRIER  { asm volatile("" ::: "memory"); __builtin_amdgcn_s_barrier(); asm volatile("" ::: "memory"); }

// Main (r12 skeleton; x-conversion fused WITHIN-step):
// BM=256 x 128ch x 3g, BK=32, 32 steps, 512 thr = 8 waves (2M x 4N).
// Wave tile 128r x 32ch x 3g: acc[3][8][2]=192 AGPR; +16 VGPR within-step x carry.
// 3-buf LDS (3 x 40KB), 1 barrier/step. Per step: issue 4 f32 x-loads (A(k+2)) +
// 3 B-gl2lds BEFORE sched_barrier; MFMA cluster; pack8+2 ds_write AFTER cluster
// (x latency hidden under MFMAs). Pack's compiler-emitted vmcnt retires B(k+1)
// in-order -> no explicit vmcnt in steady loop; lgkmcnt(0) drains ds_writes.
__global__ __launch_bounds__(512, 2) void msr_main(
    const float* __restrict__ x, const unsigned short* __restrict__ Wt,
    float* __restrict__ outacc) {
  const int bid = blockIdx.x;
  const int xcd = bid & 7;
  const int j = bid >> 3;               // 0..127 per-XCD order
  const int ct = j & 3;                 // ct fastest: same rt 4x consecutive (L2-hot x)
  const int rt = xcd * 32 + (j >> 2);   // 0..255, bijective (r12-verified)
  const int r0 = rt << 8;

  __shared__ __align__(16) unsigned char smem_[122880];  // 3 x (A 16KB | B 24KB)

  const int t = threadIdx.x;
  const int w = t >> 6, lane = t & 63;
  const int l16 = lane * 16;
  const int w3 = w * 3;
  const int ctk = ct * 32;
  const int amb = (w >> 2) * 8192;                      // A m-frag base (bytes)
  const int bread = 16384 + 6 * (w & 3) * 1024 + l16;   // B frag read base (bytes)
  const int aw0 = (w * 64 + lane) * 16;                 // A slot, chunk w (bytes)
  const int aw1 = ((8 + w) * 64 + lane) * 16;           // A slot, chunk 8+w

  // x source (r12-verified lane map): lane l -> row r0 + w*16 + (l&15),
  // k-octet l>>4 ; chunk1 rows +128 (= +131072 floats).
  const float* pXf = x + (size_t)(r0 + w * 16 + (lane & 15)) * DIN + ((lane >> 4) << 3);

  f32x4 acc[3][8][2];
#pragma unroll
  for (int g = 0; g < 3; ++g)
#pragma unroll
    for (int m = 0; m < 8; ++m)
#pragma unroll
      for (int n = 0; n < 2; ++n) acc[g][m][n] = (f32x4){0.f, 0.f, 0.f, 0.f};

#define STAGEB(KK, SB) { \
  unsigned char* _sb = smem_ + (SB) * 40960; \
  _Pragma("unroll") for (int i = 0; i < 3; ++i) \
    gl2lds16(Wt + ((size_t)(ctk + (KK)) * 24 + w3 + i) * 512 + (size_t)lane * 8, \
             _sb + 16384 + (w3 + i) * 1024); }

#define COMPUTE(KB) { \
  const unsigned char* _kb = smem_ + (KB) * 40960; \
  bf16x8 _bfr[6]; \
  _Pragma("unroll") for (int i = 0; i < 6; ++i) \
    _bfr[i] = *(const bf16x8*)(_kb + bread + i * 1024); \
  __builtin_amdgcn_s_setprio(1); \
  _Pragma("unroll") for (int m = 0; m < 8; ++m) { \
    bf16x8 _afr = *(const bf16x8*)(_kb + amb + m * 1024 + l16); \
    _Pragma("unroll") for (int g = 0; g < 3; ++g) { \
      acc[g][m][0] = __builtin_amdgcn_mfma_f32_16x16x32_bf16(_afr, _bfr[g],     acc[g][m][0], 0, 0, 0); \
      acc[g][m][1] = __builtin_amdgcn_mfma_f32_16x16x32_bf16(_afr, _bfr[3 + g], acc[g][m][1], 0, 0, 0); \
    } \
  } \
  __builtin_amdgcn_s_setprio(0); }

// step KK (buf KB=KK%3, stage into SB=(KK+2)%3): issue x(KK+2) f32 loads + B
// gl2lds; MFMA; pack+write A(KK+2); lgkm drain; barrier.
#define STEP(KB, SB, KK) { \
  const float* _pa = pXf + (size_t)((KK) + 2) * 32; \
  float4 _a0 = *(const float4*)_pa; \
  float4 _a1 = *(const float4*)(_pa + 4); \
  float4 _b0 = *(const float4*)(_pa + 131072); \
  float4 _b1 = *(const float4*)(_pa + 131076); \
  STAGEB((KK) + 2, SB); \
  SCHEDB; \
  COMPUTE(KB); \
  { unsigned char* _ab = smem_ + (SB) * 40960; \
    *(bf16x8*)(_ab + aw0) = pack8(_a0, _a1); \
    *(bf16x8*)(_ab + aw1) = pack8(_b0, _b1); } \
  WAITLGKM; \
  BARRIER; }

  // ---- prologue: A(0)->buf0, A(1)->buf1 (pack path), B(0),B(1) staged ----
  {
    float4 a0 = *(const float4*)pXf;
    float4 a1 = *(const float4*)(pXf + 4);
    float4 b0 = *(const float4*)(pXf + 131072);
    float4 b1 = *(const float4*)(pXf + 131076);
    *(bf16x8*)(smem_ + aw0) = pack8(a0, a1);
    *(bf16x8*)(smem_ + aw1) = pack8(b0, b1);
    a0 = *(const float4*)(pXf + 32);
    a1 = *(const float4*)(pXf + 36);
    b0 = *(const float4*)(pXf + 131104);
    b1 = *(const float4*)(pXf + 131108);
    *(bf16x8*)(smem_ + 40960 + aw0) = pack8(a0, a1);
    *(bf16x8*)(smem_ + 40960 + aw1) = pack8(b0, b1);
  }
  STAGEB(0, 0);
  STAGEB(1, 1);
  WAITVM3;               // retire B(0) (B(1)x3 in flight)
  WAITLGKM;
  BARRIER;

  // ---- steps 0..29 ----
#pragma unroll 1
  for (int i = 0; i < 10; ++i) {
    const int k3 = i * 3;
    STEP(0, 2, k3);
    STEP(1, 0, k3 + 1);
    STEP(2, 1, k3 + 2);
  }
  // ---- step 30 (buf 0): no stage; drain B(31) ----
  COMPUTE(0);
  WAITVM0;
  BARRIER;
  // ---- step 31 (buf 1): compute only ----
  COMPUTE(1);
#undef STEP
#undef COMPUTE
#undef STAGEB

  // ---- epilogue (r12-verified): p = (q*k)[c^1]*v[c]; fold rows; atomicAdd ----
  float pd0 = 0.f, pd1 = 0.f;
#pragma unroll
  for (int m = 0; m < 8; ++m)
#pragma unroll
    for (int r = 0; r < 4; ++r) {
      float qk0 = acc[0][m][0][r] * acc[1][m][0][r];
      float qk1 = acc[0][m][1][r] * acc[1][m][1][r];
      pd0 += __shfl_xor(qk0, 1, 64) * acc[2][m][0][r];
      pd1 += __shfl_xor(qk1, 1, 64) * acc[2][m][1][r];
    }
  pd0 += __shfl_xor(pd0, 16, 64); pd0 += __shfl_xor(pd0, 32, 64);
  pd1 += __shfl_xor(pd1, 16, 64); pd1 += __shfl_xor(pd1, 32, 64);

  // rows r0..r0+255 in h-block rt>>1 ; d = ((w&3)*32 + n*16 + (lane&15)) % 64
  if (lane < 16) {
    float* dst = &outacc[((rt >> 1) << 6) + (w & 1) * 32 + lane];
    atomicAdd(dst, pd0);
    atomicAdd(dst + 16, pd1);
  }
}

// Finish: per-batch RMSNorm -> exact gelu -> @ Wout.T (verified r1-r17)
__global__ __launch_bounds__(256) void msr_finish(
    const float* __restrict__ outacc, const float* __restrict__ gamma,
    const float* __restrict__ Wout, float* __restrict__ y) {
  const int b = blockIdx.x;
  const int t = threadIdx.x;
  __shared__ float g[V_];
  __shared__ float wsum[4];

  float v0 = outacc[b * V_ + t] * CSCALE;
  float v1 = outacc[b * V_ + 256 + t] * CSCALE;
  float ss = v0 * v0 + v1 * v1;
#pragma unroll
  for (int o = 32; o > 0; o >>= 1) ss += __shfl_down(ss, o, 64);
  if ((t & 63) == 0) wsum[t >> 6] = ss;
  __syncthreads();
  float tot = wsum[0] + wsum[1] + wsum[2] + wsum[3];
  float rs = rsqrtf(tot * (1.0f / (float)V_) + EPSF);

  float r0v = v0 * rs * gamma[t];
  float r1v = v1 * rs * gamma[t + 256];
  g[t]       = 0.5f * r0v * (1.0f + erff(r0v * 0.70710678118654752f));
  g[t + 256] = 0.5f * r1v * (1.0f + erff(r1v * 0.70710678118654752f));
  __syncthreads();

  if (t < FOUT) {
    const float* wr = Wout + (size_t)t * V_;
    float acc = 0.f;
#pragma unroll 4
    for (int c = 0; c < V_; c += 4) {
      float4 w4 = *(const float4*)(wr + c);
      acc += g[c] * w4.x + g[c + 1] * w4.y + g[c + 2] * w4.z + g[c + 3] * w4.w;
    }
    y[b * FOUT + t] = acc;
  }
}

extern "C" void kernel_launch(void* const* d_in, const int* in_sizes, int n_in,
                              void* d_out, int out_size, void* d_ws, size_t ws_size,
                              hipStream_t stream) {
  const float* x     = (const float*)d_in[0];
  const float* Wq    = (const float*)d_in[1];
  const float* Wk    = (const float*)d_in[2];
  const float* Wv    = (const float*)d_in[3];
  const float* Wout  = (const float*)d_in[4];
  const float* gamma = (const float*)d_in[5];

  float* outacc = (float*)d_ws;                                  // 32 KB
  unsigned short* Wt = (unsigned short*)((char*)d_ws + 32768);   // 3 MB bf16 weights
  float* y = (float*)d_out;

  msr_conv<<<769, 256, 0, stream>>>(Wq, Wk, Wv, Wt, outacc);
  msr_main<<<1024, 512, 0, stream>>>(x, Wt, outacc);
  msr_finish<<<B_, 256, 0, stream>>>(outacc, gamma, Wout, y);
}

// Round 19
// 244.095 us; speedup vs baseline: 1.3278x; 1.3278x over previous
//
#include <hip/hip_runtime.h>
#include <hip/hip_bf16.h>
#include <math.h>

#define B_   16
#define S_   4096
#define DIN  1024
#define V_   512
#define FOUT 120

typedef __attribute__((ext_vector_type(8))) short bf16x8;
typedef __attribute__((ext_vector_type(4))) float f32x4;

#define AS1 __attribute__((address_space(1)))
#define AS3 __attribute__((address_space(3)))

__device__ const float CSCALE = 0.1f / (64.0f * 4096.0f);
__device__ const float EPSF = 1e-5f;

__device__ inline void gl2lds16(const void* g, void* l) {
  __builtin_amdgcn_global_load_lds((const AS1 unsigned int*)g,
                                   (AS3 unsigned int*)l, 16, 0, 0);
}

// fp32 -> bf16 RNE
__device__ inline unsigned short f2b(float f) {
  unsigned u = __builtin_bit_cast(unsigned, f);
  unsigned r = (u + 0x7FFFu + ((u >> 16) & 1u)) >> 16;
  return (unsigned short)r;
}

__device__ inline bf16x8 pack8(float4 a, float4 b) {
  bf16x8 r;
  r[0] = (short)f2b(a.x); r[1] = (short)f2b(a.y);
  r[2] = (short)f2b(a.z); r[3] = (short)f2b(a.w);
  r[4] = (short)f2b(b.x); r[5] = (short)f2b(b.y);
  r[6] = (short)f2b(b.z); r[7] = (short)f2b(b.w);
  return r;
}

// Fused pre-pass: blocks 0..767 convert W (frag-major Wt, r7-r17-verified map);
// blocks 768..2815 convert x -> Xb bf16 (grid-stride, r6-r17-verified);
// last block zeroes outacc. Whole blocks per role -> no divergence.
template <bool DOX>
__global__ __launch_bounds__(256) void msr_conv(
    const float* __restrict__ Wq, const float* __restrict__ Wk,
    const float* __restrict__ Wv, const float* __restrict__ x,
    unsigned short* __restrict__ Wt, unsigned short* __restrict__ Xb,
    float* __restrict__ outacc) {
  const int bid = blockIdx.x;
  if (bid < 768) {
    // Wt frag-major: chunk e = ((ct*32 + k)*24 + f)*64 + l ; f = 3*nf + g
    // lane l: channel ct*128 + nf*16 + (l&15), k-elem k*32 + (l>>4)*8
    int e = bid * 256 + threadIdx.x;
    int l = e & 63;
    int f = (e >> 6) % 24;
    int ck = (e >> 6) / 24;
    int k = ck & 31;
    int ct = ck >> 5;
    int nf = f / 3, g = f % 3;
    const float* W = (g == 0) ? Wq : (g == 1) ? Wk : Wv;
    int ch = ct * 128 + nf * 16 + (l & 15);
    const float* src = W + (size_t)ch * DIN + k * 32 + (l >> 4) * 8;
    float4 a = *(const float4*)src;
    float4 b = *(const float4*)(src + 4);
    *(bf16x8*)(Wt + (size_t)e * 8) = pack8(a, b);
  } else if (DOX && bid < 2816) {
    const size_t stride = 2048ull * 256;
    for (size_t i = (size_t)(bid - 768) * 256 + threadIdx.x; i < 8388608ull; i += stride) {
      const float* src = x + i * 8;
      float4 a = *(const float4*)src;
      float4 b = *(const float4*)(src + 4);
      *(bf16x8*)(Xb + i * 8) = pack8(a, b);
    }
  } else {
    for (int i = threadIdx.x; i < B_ * V_; i += 256) outacc[i] = 0.f;
  }
}

#define WAITVM5  asm volatile("s_waitcnt vmcnt(5)" ::: "memory")
#define WAITVM3  asm volatile("s_waitcnt vmcnt(3)" ::: "memory")
#define WAITVM0  asm volatile("s_waitcnt vmcnt(0)" ::: "memory")
#define WAITLGKM asm volatile("s_waitcnt lgkmcnt(0)" ::: "memory")
#define SCHEDB   __builtin_amdgcn_sched_barrier(0)
#define BARRIER  { asm volatile("" ::: "memory"); __builtin_amdgcn_s_barrier(); asm volatile("" ::: "memory"); }

// Main — r12 VERBATIM (measured optimum: 174 us, MfmaUtil 52%, 0 conflicts):
// BM=256 x 128ch x 3g, BK=32, 32 steps, 512 thr = 8 waves (2M x 4N).
// Wave tile 128r x 32ch x 3g: acc[3][8][2] = 192 AGPR, bfr[6] held, afr streamed.
// 3-buf LDS pipeline (3 x 40KB), 1 barrier/step, counted vmcnt(5) (2 A + 3 B gl2lds).
template <bool DIRECT>
__global__ __launch_bounds__(512, 2) void msr_main(
    const float* __restrict__ x, const unsigned short* __restrict__ Xb,
    const unsigned short* __restrict__ Wt, float* __restrict__ outacc) {
  const int bid = blockIdx.x;
  const int xcd = bid & 7;
  const int j = bid >> 3;               // 0..127 per-XCD order
  const int ct = j & 3;                 // ct fastest: same rt 4x consecutive (L2-hot x)
  const int rt = xcd * 32 + (j >> 2);   // 0..255, bijective (r12-verified)
  const int r0 = rt << 8;

  __shared__ __align__(16) unsigned char smem_[122880];  // 3 x (A 16KB | B 24KB)

  const int t = threadIdx.x;
  const int w = t >> 6, lane = t & 63;
  const int l16 = lane * 16;
  const int w3 = w * 3;
  const int ctk = ct * 32;
  const int amb = (w >> 2) * 8192;                      // A m-frag base (bytes)
  const int bread = 16384 + 6 * (w & 3) * 1024 + l16;   // B frag read base (bytes)

  const unsigned short* srcA0 =
      Xb + (size_t)(r0 + w * 16 + (lane & 15)) * DIN + ((lane >> 4) << 3);
  const unsigned short* srcA1 = srcA0 + (size_t)128 * DIN;
  const float* pXf = x + (size_t)(r0 + w * 16 + (lane & 15)) * DIN + ((lane >> 4) << 3);

  f32x4 acc[3][8][2];
#pragma unroll
  for (int g = 0; g < 3; ++g)
#pragma unroll
    for (int m = 0; m < 8; ++m)
#pragma unroll
      for (int n = 0; n < 2; ++n) acc[g][m][n] = (f32x4){0.f, 0.f, 0.f, 0.f};

#define STAGE(KK, SB) { \
  unsigned char* _sb = smem_ + (SB) * 40960; \
  if constexpr (DIRECT) { \
    gl2lds16(srcA0 + (size_t)(KK) * 32, _sb + w * 1024); \
    gl2lds16(srcA1 + (size_t)(KK) * 32, _sb + (8 + w) * 1024); \
  } else { \
    const float* _p0 = pXf + (size_t)(KK) * 32; \
    const float* _p1 = _p0 + (size_t)128 * DIN; \
    *(bf16x8*)(_sb + (w * 64 + lane) * 16) = \
        pack8(*(const float4*)_p0, *(const float4*)(_p0 + 4)); \
    *(bf16x8*)(_sb + ((8 + w) * 64 + lane) * 16) = \
        pack8(*(const float4*)_p1, *(const float4*)(_p1 + 4)); \
  } \
  _Pragma("unroll") for (int i = 0; i < 3; ++i) \
    gl2lds16(Wt + ((size_t)(ctk + (KK)) * 24 + w3 + i) * 512 + (size_t)lane * 8, \
             _sb + 16384 + (w3 + i) * 1024); }

#define COMPUTE(KB) { \
  const unsigned char* _kb = smem_ + (KB) * 40960; \
  bf16x8 _bfr[6]; \
  _Pragma("unroll") for (int i = 0; i < 6; ++i) \
    _bfr[i] = *(const bf16x8*)(_kb + bread + i * 1024); \
  __builtin_amdgcn_s_setprio(1); \
  _Pragma("unroll") for (int m = 0; m < 8; ++m) { \
    bf16x8 _afr = *(const bf16x8*)(_kb + amb + m * 1024 + l16); \
    _Pragma("unroll") for (int g = 0; g < 3; ++g) { \
      acc[g][m][0] = __builtin_amdgcn_mfma_f32_16x16x32_bf16(_afr, _bfr[g],     acc[g][m][0], 0, 0, 0); \
      acc[g][m][1] = __builtin_amdgcn_mfma_f32_16x16x32_bf16(_afr, _bfr[3 + g], acc[g][m][1], 0, 0, 0); \
    } \
  } \
  __builtin_amdgcn_s_setprio(0); }

#define STEP(KB, SB, KK, DOSTAGE, VMD, VMF) { \
  if (DOSTAGE) { STAGE((KK) + 2, SB); } \
  SCHEDB; \
  COMPUTE(KB); \
  if constexpr (DIRECT) { VMD; } else { WAITLGKM; VMF; } \
  BARRIER; }

  // ---- prologue: stage steps 0,1 into bufs 0,1 ----
  STAGE(0, 0);
  STAGE(1, 1);
  if constexpr (DIRECT) { WAITVM5; } else { WAITLGKM; WAITVM3; }
  BARRIER;

  // ---- steps 0..29 ----
#pragma unroll 1
  for (int i = 0; i < 10; ++i) {
    const int k3 = i * 3;
    STEP(0, 2, k3,     1, WAITVM5, WAITVM3);
    STEP(1, 0, k3 + 1, 1, WAITVM5, WAITVM3);
    STEP(2, 1, k3 + 2, 1, WAITVM5, WAITVM3);
  }
  // ---- step 30: no stage; full drain (incl. stage(31)) ----
  STEP(0, 0, 30, 0, WAITVM0, WAITVM0);
  // ---- step 31: compute only ----
  COMPUTE(1);
#undef STEP
#undef COMPUTE
#undef STAGE

  // ---- epilogue (r12-verified): p = (q*k)[c^1]*v[c]; fold rows; atomicAdd ----
  float pd0 = 0.f, pd1 = 0.f;
#pragma unroll
  for (int m = 0; m < 8; ++m)
#pragma unroll
    for (int r = 0; r < 4; ++r) {
      float qk0 = acc[0][m][0][r] * acc[1][m][0][r];
      float qk1 = acc[0][m][1][r] * acc[1][m][1][r];
      pd0 += __shfl_xor(qk0, 1, 64) * acc[2][m][0][r];
      pd1 += __shfl_xor(qk1, 1, 64) * acc[2][m][1][r];
    }
  pd0 += __shfl_xor(pd0, 16, 64); pd0 += __shfl_xor(pd0, 32, 64);
  pd1 += __shfl_xor(pd1, 16, 64); pd1 += __shfl_xor(pd1, 32, 64);

  // rows r0..r0+255 in h-block rt>>1 ; d = ((w&3)*32 + n*16 + (lane&15)) % 64
  if (lane < 16) {
    float* dst = &outacc[((rt >> 1) << 6) + (w & 1) * 32 + lane];
    atomicAdd(dst, pd0);
    atomicAdd(dst + 16, pd1);
  }
}

// Finish: per-batch RMSNorm -> exact gelu -> @ Wout.T (verified r1-r18)
__global__ __launch_bounds__(256) void msr_finish(
    const float* __restrict__ outacc, const float* __restrict__ gamma,
    const float* __restrict__ Wout, float* __restrict__ y) {
  const int b = blockIdx.x;
  const int t = threadIdx.x;
  __shared__ float g[V_];
  __shared__ float wsum[4];

  float v0 = outacc[b * V_ + t] * CSCALE;
  float v1 = outacc[b * V_ + 256 + t] * CSCALE;
  float ss = v0 * v0 + v1 * v1;
#pragma unroll
  for (int o = 32; o > 0; o >>= 1) ss += __shfl_down(ss, o, 64);
  if ((t & 63) == 0) wsum[t >> 6] = ss;
  __syncthreads();
  float tot = wsum[0] + wsum[1] + wsum[2] + wsum[3];
  float rs = rsqrtf(tot * (1.0f / (float)V_) + EPSF);

  float r0v = v0 * rs * gamma[t];
  float r1v = v1 * rs * gamma[t + 256];
  g[t]       = 0.5f * r0v * (1.0f + erff(r0v * 0.70710678118654752f));
  g[t + 256] = 0.5f * r1v * (1.0f + erff(r1v * 0.70710678118654752f));
  __syncthreads();

  if (t < FOUT) {
    const float* wr = Wout + (size_t)t * V_;
    float acc = 0.f;
#pragma unroll 4
    for (int c = 0; c < V_; c += 4) {
      float4 w4 = *(const float4*)(wr + c);
      acc += g[c] * w4.x + g[c + 1] * w4.y + g[c + 2] * w4.z + g[c + 3] * w4.w;
    }
    y[b * FOUT + t] = acc;
  }
}

extern "C" void kernel_launch(void* const* d_in, const int* in_sizes, int n_in,
                              void* d_out, int out_size, void* d_ws, size_t ws_size,
                              hipStream_t stream) {
  const float* x     = (const float*)d_in[0];
  const float* Wq    = (const float*)d_in[1];
  const float* Wk    = (const float*)d_in[2];
  const float* Wv    = (const float*)d_in[3];
  const float* Wout  = (const float*)d_in[4];
  const float* gamma = (const float*)d_in[5];

  float* outacc = (float*)d_ws;                                    // 32 KB
  unsigned short* Wt = (unsigned short*)((char*)d_ws + 32768);     // 3 MB
  unsigned short* Xb = (unsigned short*)((char*)d_ws + 32768 + 3145728);  // 128 MB
  float* y = (float*)d_out;

  const size_t need = 32768ull + 3145728ull + 134217728ull;

  if (ws_size >= need) {
    msr_conv<true><<<2817, 256, 0, stream>>>(Wq, Wk, Wv, x, Wt, Xb, outacc);
    msr_main<true><<<1024, 512, 0, stream>>>(x, Xb, Wt, outacc);
  } else {
    msr_conv<false><<<769, 256, 0, stream>>>(Wq, Wk, Wv, x, Wt, Xb, outacc);
    msr_main<false><<<1024, 512, 0, stream>>>(x, Xb, Wt, outacc);
  }
  msr_finish<<<B_, 256, 0, stream>>>(outacc, gamma, Wout, y);
}